// Round 1
// baseline (2747.496 us; speedup 1.0000x reference)
//
#include <hip/hip_runtime.h>
#include <hip/hip_bf16.h>
#include <math.h>

// Problem constants (fixed by reference setup_inputs)
#define BB 2
#define SS 2048
#define HH 1024
#define NH 16
#define HD 64

// ---------------------------------------------------------------------------
// GEMM: C[M,N] = A[M,K] @ W[N,K]^T + bias[N]   (both K-contiguous, "NT")
// BM=128, BN=64, BK=16, 256 threads, 8x4 micro-tile per thread.
// ---------------------------------------------------------------------------
__global__ __launch_bounds__(256) void gemm_nt_bias(
    const float* __restrict__ A, const float* __restrict__ W,
    const float* __restrict__ bias, float* __restrict__ C,
    int M, int N, int K)
{
    __shared__ float As[16][132];   // [k][m], pad breaks store conflicts
    __shared__ float Bs[16][68];    // [k][n]

    const int tid = threadIdx.x;
    const int m0 = blockIdx.y * 128;
    const int n0 = blockIdx.x * 64;
    const int tx = tid & 15;        // n micro index
    const int ty = tid >> 4;        // m micro index

    float acc[8][4];
#pragma unroll
    for (int i = 0; i < 8; ++i)
#pragma unroll
        for (int j = 0; j < 4; ++j) acc[i][j] = 0.f;

    const int arow = tid >> 1, ac = (tid & 1) * 8;   // A tile loader
    const int brow = tid >> 2, bc = (tid & 3) * 4;   // B tile loader

    for (int kb = 0; kb < K; kb += 16) {
        float4 a0 = *(const float4*)&A[(size_t)(m0 + arow) * K + kb + ac];
        float4 a1 = *(const float4*)&A[(size_t)(m0 + arow) * K + kb + ac + 4];
        float4 b0 = *(const float4*)&W[(size_t)(n0 + brow) * K + kb + bc];
        __syncthreads();   // previous iter's LDS reads done before overwrite
        As[ac + 0][arow] = a0.x; As[ac + 1][arow] = a0.y;
        As[ac + 2][arow] = a0.z; As[ac + 3][arow] = a0.w;
        As[ac + 4][arow] = a1.x; As[ac + 5][arow] = a1.y;
        As[ac + 6][arow] = a1.z; As[ac + 7][arow] = a1.w;
        Bs[bc + 0][brow] = b0.x; Bs[bc + 1][brow] = b0.y;
        Bs[bc + 2][brow] = b0.z; Bs[bc + 3][brow] = b0.w;
        __syncthreads();
#pragma unroll
        for (int kk = 0; kk < 16; ++kk) {
            float4 av0 = *(const float4*)&As[kk][ty * 8];
            float4 av1 = *(const float4*)&As[kk][ty * 8 + 4];
            float4 bv  = *(const float4*)&Bs[kk][tx * 4];
            float am[8] = {av0.x, av0.y, av0.z, av0.w, av1.x, av1.y, av1.z, av1.w};
            float bm[4] = {bv.x, bv.y, bv.z, bv.w};
#pragma unroll
            for (int i = 0; i < 8; ++i)
#pragma unroll
                for (int j = 0; j < 4; ++j) acc[i][j] += am[i] * bm[j];
        }
    }

    float4 bvec = *(const float4*)&bias[n0 + tx * 4];
#pragma unroll
    for (int i = 0; i < 8; ++i) {
        int m = m0 + ty * 8 + i;
        float4 o;
        o.x = acc[i][0] + bvec.x; o.y = acc[i][1] + bvec.y;
        o.z = acc[i][2] + bvec.z; o.w = acc[i][3] + bvec.w;
        *(float4*)&C[(size_t)m * N + n0 + tx * 4] = o;
    }
}

// ---------------------------------------------------------------------------
// Fused attention: per block = (b, h, 4 q-rows).
//   phase 1: scores (QK^T * scale, key-mask) -> LDS  [4][2048]
//   phase 2: row softmax (wave w owns row w), write weights to d_out
//   phase 3: PV accumulate -> ctx
// K/V staged through LDS in 64-key chunks.
// ---------------------------------------------------------------------------
__global__ __launch_bounds__(256) void attn_fused(
    const float* __restrict__ Q, const float* __restrict__ K,
    const float* __restrict__ V, const int* __restrict__ mask,
    float* __restrict__ attn, float* __restrict__ ctx)
{
    __shared__ __align__(16) float qs[4][64];
    __shared__ __align__(16) float kv[64][68];   // [key][dim], pad 68
    __shared__ __align__(16) float sc[4][2048];

    const int q0   = blockIdx.x * 4;
    const int h    = blockIdx.y;
    const int b    = blockIdx.z;
    const int tid  = threadIdx.x;
    const int lane = tid & 63;
    const int wv   = tid >> 6;     // wave id == owned q-row (0..3)

    // load q rows
    qs[wv][lane] = Q[((size_t)(b * SS + q0 + wv)) * HH + h * HD + lane];
    __syncthreads();

    const float* Kb = K + ((size_t)b * SS) * HH + h * HD;
    const float* Vb = V + ((size_t)b * SS) * HH + h * HD;

    // ---- phase 1: scores ----
    for (int c = 0; c < SS / 64; ++c) {
        const int j0 = c * 64;
        {   // cooperative K-chunk load: [64 keys][64 dims]
            const int jj = tid >> 2, dd = (tid & 3) * 16;
            const float4* g = (const float4*)(Kb + (size_t)(j0 + jj) * HH + dd);
            float4 v0 = g[0], v1 = g[1], v2 = g[2], v3 = g[3];
            float4* s = (float4*)&kv[jj][dd];
            s[0] = v0; s[1] = v1; s[2] = v2; s[3] = v3;
        }
        __syncthreads();
        float acc = 0.f;
        const float4* q4 = (const float4*)qs[wv];
        const float4* k4 = (const float4*)kv[lane];
#pragma unroll
        for (int d4 = 0; d4 < 16; ++d4) {
            float4 a = q4[d4], kk = k4[d4];
            acc += a.x * kk.x + a.y * kk.y + a.z * kk.z + a.w * kk.w;
        }
        float scv = acc * 0.125f;              // hd^-0.5
        if (mask[b * SS + j0 + lane] == 0) scv = -10000.0f;
        sc[wv][j0 + lane] = scv;
        __syncthreads();
    }

    // ---- phase 2: softmax (wave wv owns row wv) ----
    float m = -1e30f;
    for (int t = lane; t < SS; t += 64) m = fmaxf(m, sc[wv][t]);
#pragma unroll
    for (int off = 32; off; off >>= 1) m = fmaxf(m, __shfl_down(m, off));
    m = __shfl(m, 0);
    float sum = 0.f;
    for (int t = lane; t < SS; t += 64) {
        float e = __expf(sc[wv][t] - m);
        sc[wv][t] = e;
        sum += e;
    }
#pragma unroll
    for (int off = 32; off; off >>= 1) sum += __shfl_down(sum, off);
    sum = __shfl(sum, 0);
    const float inv = 1.0f / sum;
    float* arow = attn + ((size_t)(b * NH + h) * SS + q0 + wv) * SS;
    for (int t = lane; t < SS; t += 64) {
        float w = sc[wv][t] * inv;
        sc[wv][t] = w;
        arow[t] = w;
    }

    // ---- phase 3: PV ----
    float4 c4 = {0.f, 0.f, 0.f, 0.f};
    const int jg = lane >> 4;          // key sub-group 0..3
    const int d4 = (lane & 15) * 4;    // dim quad
    for (int c = 0; c < SS / 64; ++c) {
        const int j0 = c * 64;
        {   // cooperative V-chunk load
            const int jj = tid >> 2, dd = (tid & 3) * 16;
            const float4* g = (const float4*)(Vb + (size_t)(j0 + jj) * HH + dd);
            float4 v0 = g[0], v1 = g[1], v2 = g[2], v3 = g[3];
            float4* s = (float4*)&kv[jj][dd];
            s[0] = v0; s[1] = v1; s[2] = v2; s[3] = v3;
        }
        __syncthreads();
#pragma unroll
        for (int jj = 0; jj < 16; ++jj) {
            const int j = jg * 16 + jj;
            float w = sc[wv][j0 + j];
            float4 vvv = *(const float4*)&kv[j][d4];
            c4.x += w * vvv.x; c4.y += w * vvv.y;
            c4.z += w * vvv.z; c4.w += w * vvv.w;
        }
        __syncthreads();
    }
    // reduce partials across the 4 key sub-groups (lanes l, l+16, l+32, l+48)
    c4.x += __shfl_down(c4.x, 32); c4.y += __shfl_down(c4.y, 32);
    c4.z += __shfl_down(c4.z, 32); c4.w += __shfl_down(c4.w, 32);
    c4.x += __shfl_down(c4.x, 16); c4.y += __shfl_down(c4.y, 16);
    c4.z += __shfl_down(c4.z, 16); c4.w += __shfl_down(c4.w, 16);
    if (lane < 16) {
        float* cp = ctx + ((size_t)(b * SS + q0 + wv)) * HH + h * HD + d4;
        *(float4*)cp = c4;
    }
}

// ---------------------------------------------------------------------------
// out = P1 * sigmoid(P2), vectorized
// ---------------------------------------------------------------------------
__global__ __launch_bounds__(256) void gate_mul(
    const float4* __restrict__ P1, const float4* __restrict__ P2,
    float4* __restrict__ out, int n4)
{
    int i = blockIdx.x * 256 + threadIdx.x;
    if (i < n4) {
        float4 a = P1[i], g = P2[i], o;
        o.x = a.x / (1.f + __expf(-g.x));
        o.y = a.y / (1.f + __expf(-g.y));
        o.z = a.z / (1.f + __expf(-g.z));
        o.w = a.w / (1.f + __expf(-g.w));
        out[i] = o;
    }
}

// ---------------------------------------------------------------------------
extern "C" void kernel_launch(void* const* d_in, const int* in_sizes, int n_in,
                              void* d_out, int out_size, void* d_ws, size_t ws_size,
                              hipStream_t stream)
{
    const float* x    = (const float*)d_in[0];
    const int*   mask = (const int*)d_in[1];
    const float* wq = (const float*)d_in[2];  const float* bq = (const float*)d_in[3];
    const float* wk = (const float*)d_in[4];  const float* bk = (const float*)d_in[5];
    const float* wv = (const float*)d_in[6];  const float* bv = (const float*)d_in[7];
    const float* wo = (const float*)d_in[8];  const float* bo = (const float*)d_in[9];
    const float* wg = (const float*)d_in[10]; const float* bg = (const float*)d_in[11];

    const int M = BB * SS;                 // 4096
    const size_t NTOK = (size_t)M * HH;    // 4,194,304

    float* out_main = (float*)d_out;             // [B,S,H]
    float* out_attn = (float*)d_out + NTOK;      // [B,nh,S,S]

    float* Q   = (float*)d_ws;
    float* Kp  = Q + NTOK;
    float* Vp  = Kp + NTOK;
    float* CTX = Vp + NTOK;
    float* P1  = Q;    // alias: Q dead after attention
    float* P2  = Kp;   // alias: K dead after attention

    dim3 gemm_grid(HH / 64, M / 128);      // (16, 32)
    gemm_nt_bias<<<gemm_grid, 256, 0, stream>>>(x, wq, bq, Q,  M, HH, HH);
    gemm_nt_bias<<<gemm_grid, 256, 0, stream>>>(x, wk, bk, Kp, M, HH, HH);
    gemm_nt_bias<<<gemm_grid, 256, 0, stream>>>(x, wv, bv, Vp, M, HH, HH);

    dim3 attn_grid(SS / 4, NH, BB);        // (512, 16, 2)
    attn_fused<<<attn_grid, 256, 0, stream>>>(Q, Kp, Vp, mask, out_attn, CTX);

    gemm_nt_bias<<<gemm_grid, 256, 0, stream>>>(CTX, wo, bo, P1, M, HH, HH);
    gemm_nt_bias<<<gemm_grid, 256, 0, stream>>>(CTX, wg, bg, P2, M, HH, HH);

    int n4 = (int)(NTOK / 4);
    gate_mul<<<(n4 + 255) / 256, 256, 0, stream>>>(
        (const float4*)P1, (const float4*)P2, (float4*)out_main, n4);
}

// Round 2
// 1282.551 us; speedup vs baseline: 2.1422x; 2.1422x over previous
//
#include <hip/hip_runtime.h>
#include <math.h>

#define BB 2
#define SS 2048
#define HH 1024
#define NH 16
#define HD 64
#define LDK 40   // LDS row stride in shorts (32 + 8 pad -> stride-20-dword rows, 2-way max)

typedef __attribute__((ext_vector_type(8))) short short8;   // 8 bf16 (4 VGPRs)
typedef __attribute__((ext_vector_type(4))) float floatx4;  // MFMA acc

__device__ __forceinline__ unsigned short f2bf(float f) {
    unsigned u = __float_as_uint(f);
    u += 0x7FFF + ((u >> 16) & 1);          // RNE
    return (unsigned short)(u >> 16);
}
__device__ __forceinline__ float bf2f(unsigned short h) {
    return __uint_as_float((unsigned)h << 16);
}

// ---------------------------------------------------------------------------
// Split-bf16 MFMA GEMM: C[M,N] = A[M,K] @ B[N,K]^T  (both K-contiguous)
// BM=128 fixed, BN in {64,128}. 256 threads = 4 waves in 2x2.
// A = Ah+Al, B = Bh+Bl (bf16 each); acc += Ah*Bh + Ah*Bl + Al*Bh  (~f32 acc.)
// MODE 0: += bias[col]          (projections)
// MODE 1: v = mask ? v*0.125 : -10000   (QK^T scores, batched over z=b*16+h)
// MODE 2: plain                 (PV, batched)
// ---------------------------------------------------------------------------
template<int BN, int MODE>
__global__ __launch_bounds__(256) void mfma_gemm(
    const float* __restrict__ A, const float* __restrict__ B,
    const float* __restrict__ bias, float* __restrict__ C,
    int K, int lda, int ldb, int ldc,
    long long sAb, long long sAh, long long sBb, long long sBh,
    long long sCb, long long sCh, const int* __restrict__ mask)
{
    constexpr int BM = 128;
    constexpr int MT = 4;            // 16-row tiles per wave (wave = 64 rows)
    constexpr int NT = BN / 32;      // 16-col tiles per wave (wave = BN/2 cols)
    __shared__ __attribute__((aligned(16))) unsigned short AhS[BM * LDK];
    __shared__ __attribute__((aligned(16))) unsigned short AlS[BM * LDK];
    __shared__ __attribute__((aligned(16))) unsigned short BhS[BN * LDK];
    __shared__ __attribute__((aligned(16))) unsigned short BlS[BN * LDK];

    const int tid  = threadIdx.x;
    const int wave = tid >> 6, lane = tid & 63;
    const int wm = wave >> 1, wn = wave & 1;
    const int r16 = lane & 15, quad = lane >> 4;

    const int z  = blockIdx.z;
    const int bz = z >> 4, hz = z & 15;
    const float* Ab = A + (size_t)(bz * sAb + hz * sAh);
    const float* Bb = B + (size_t)(bz * sBb + hz * sBh);
    float*       Cb = C + (size_t)(bz * sCb + hz * sCh);

    const int m0 = blockIdx.y * BM;
    const int n0 = blockIdx.x * BN;

    floatx4 acc[MT][NT];
#pragma unroll
    for (int i = 0; i < MT; ++i)
#pragma unroll
        for (int j = 0; j < NT; ++j) acc[i][j] = (floatx4){0.f, 0.f, 0.f, 0.f};

    // staging index maps (256 threads cover ROWSx32 f32 tile)
    const int arow = tid >> 1,  ac = (tid & 1) * 16;                       // 16 f32/thr
    const int brow = (BN == 128) ? (tid >> 1) : (tid >> 2);
    const int bc   = (BN == 128) ? ((tid & 1) * 16) : ((tid & 3) * 8);
    constexpr int ANV = 16, BNV = (BN == 128) ? 16 : 8;

    const float* aptr = Ab + (size_t)(m0 + arow) * lda + ac;
    const float* bptr = Bb + (size_t)(n0 + brow) * ldb + bc;

    for (int kb = 0; kb < K; kb += 32) {
        float ar[ANV], br[BNV];
#pragma unroll
        for (int i = 0; i < ANV / 4; ++i) {
            float4 v = *(const float4*)(aptr + kb + i * 4);
            ar[4*i] = v.x; ar[4*i+1] = v.y; ar[4*i+2] = v.z; ar[4*i+3] = v.w;
        }
#pragma unroll
        for (int i = 0; i < BNV / 4; ++i) {
            float4 v = *(const float4*)(bptr + kb + i * 4);
            br[4*i] = v.x; br[4*i+1] = v.y; br[4*i+2] = v.z; br[4*i+3] = v.w;
        }
        __syncthreads();   // previous iter's frag reads complete
#pragma unroll
        for (int g = 0; g < ANV / 8; ++g) {
            union { unsigned short s[8]; uint4 v; } uh, ul;
#pragma unroll
            for (int j = 0; j < 8; ++j) {
                float xx = ar[g*8 + j];
                unsigned short h = f2bf(xx);
                uh.s[j] = h;
                ul.s[j] = f2bf(xx - bf2f(h));
            }
            *(uint4*)&AhS[arow * LDK + ac + g*8] = uh.v;
            *(uint4*)&AlS[arow * LDK + ac + g*8] = ul.v;
        }
#pragma unroll
        for (int g = 0; g < BNV / 8; ++g) {
            union { unsigned short s[8]; uint4 v; } uh, ul;
#pragma unroll
            for (int j = 0; j < 8; ++j) {
                float xx = br[g*8 + j];
                unsigned short h = f2bf(xx);
                uh.s[j] = h;
                ul.s[j] = f2bf(xx - bf2f(h));
            }
            *(uint4*)&BhS[brow * LDK + bc + g*8] = uh.v;
            *(uint4*)&BlS[brow * LDK + bc + g*8] = ul.v;
        }
        __syncthreads();

        // fragment reads: lane holds X[idx16 = lane&15][k = quad*8 + j]
        short8 fah[MT], fal[MT], fbh[NT], fbl[NT];
#pragma unroll
        for (int mt = 0; mt < MT; ++mt) {
            int r = (wm * 64 + mt * 16 + r16) * LDK + quad * 8;
            fah[mt] = *(const short8*)&AhS[r];
            fal[mt] = *(const short8*)&AlS[r];
        }
#pragma unroll
        for (int nt = 0; nt < NT; ++nt) {
            int r = (wn * (BN/2) + nt * 16 + r16) * LDK + quad * 8;
            fbh[nt] = *(const short8*)&BhS[r];
            fbl[nt] = *(const short8*)&BlS[r];
        }
#pragma unroll
        for (int mt = 0; mt < MT; ++mt)
#pragma unroll
            for (int nt = 0; nt < NT; ++nt) {
                acc[mt][nt] = __builtin_amdgcn_mfma_f32_16x16x32_bf16(fah[mt], fbh[nt], acc[mt][nt], 0, 0, 0);
                acc[mt][nt] = __builtin_amdgcn_mfma_f32_16x16x32_bf16(fah[mt], fbl[nt], acc[mt][nt], 0, 0, 0);
                acc[mt][nt] = __builtin_amdgcn_mfma_f32_16x16x32_bf16(fal[mt], fbh[nt], acc[mt][nt], 0, 0, 0);
            }
    }

    // epilogue: C/D layout col = lane&15, row = quad*4 + reg  [m89-verified]
#pragma unroll
    for (int nt = 0; nt < NT; ++nt) {
        const int col = n0 + wn * (BN/2) + nt * 16 + r16;
        float bval = 0.f; int mv = 1;
        if (MODE == 0) bval = bias[col];
        if (MODE == 1) mv = mask[bz * 2048 + col];
#pragma unroll
        for (int mt = 0; mt < MT; ++mt) {
            const int rowb = m0 + wm * 64 + mt * 16 + quad * 4;
#pragma unroll
            for (int r = 0; r < 4; ++r) {
                float v = acc[mt][nt][r];
                if (MODE == 0) v += bval;
                if (MODE == 1) v = mv ? v * 0.125f : -10000.0f;
                Cb[(size_t)(rowb + r) * ldc + col] = v;
            }
        }
    }
}

// ---------------------------------------------------------------------------
// V transpose per head: VT[(b*NH+h)][d][k] = V[(b*SS+k)*HH + h*HD + d]
// ---------------------------------------------------------------------------
__global__ __launch_bounds__(256) void vtranspose(
    const float* __restrict__ V, float* __restrict__ VT)
{
    __shared__ float t[64][65];
    const int k0 = blockIdx.x * 64;
    const int h  = blockIdx.y;
    const int b  = blockIdx.z;
    const int tid = threadIdx.x;
    {
        const int row = tid >> 2, c0 = (tid & 3) * 16;
        const float* g = V + (size_t)(b * SS + k0 + row) * HH + h * HD + c0;
#pragma unroll
        for (int i = 0; i < 4; ++i) {
            float4 v = *(const float4*)(g + i * 4);
            t[row][c0 + i*4 + 0] = v.x; t[row][c0 + i*4 + 1] = v.y;
            t[row][c0 + i*4 + 2] = v.z; t[row][c0 + i*4 + 3] = v.w;
        }
    }
    __syncthreads();
    {
        const int d = tid >> 2, kg = (tid & 3) * 16;
        float* o = VT + ((size_t)(b * NH + h) * HD + d) * SS + k0 + kg;
#pragma unroll
        for (int i = 0; i < 4; ++i) {
            float4 v;
            v.x = t[kg + i*4 + 0][d]; v.y = t[kg + i*4 + 1][d];
            v.z = t[kg + i*4 + 2][d]; v.w = t[kg + i*4 + 3][d];
            *(float4*)(o + i * 4) = v;
        }
    }
}

// ---------------------------------------------------------------------------
// Row softmax in place, one wave per 2048-length row, row held in registers.
// ---------------------------------------------------------------------------
__global__ __launch_bounds__(256) void softmax_rows(float* __restrict__ attn)
{
    const int wave = threadIdx.x >> 6, lane = threadIdx.x & 63;
    float* p = attn + ((size_t)blockIdx.x * 4 + wave) * 2048 + lane * 4;
    float4 v[8];
#pragma unroll
    for (int i = 0; i < 8; ++i) v[i] = *(const float4*)(p + i * 256);
    float m = -1e30f;
#pragma unroll
    for (int i = 0; i < 8; ++i)
        m = fmaxf(m, fmaxf(fmaxf(v[i].x, v[i].y), fmaxf(v[i].z, v[i].w)));
#pragma unroll
    for (int off = 32; off; off >>= 1) m = fmaxf(m, __shfl_xor(m, off));
    float s = 0.f;
#pragma unroll
    for (int i = 0; i < 8; ++i) {
        v[i].x = __expf(v[i].x - m); v[i].y = __expf(v[i].y - m);
        v[i].z = __expf(v[i].z - m); v[i].w = __expf(v[i].w - m);
        s += v[i].x + v[i].y + v[i].z + v[i].w;
    }
#pragma unroll
    for (int off = 32; off; off >>= 1) s += __shfl_xor(s, off);
    const float inv = 1.0f / s;
#pragma unroll
    for (int i = 0; i < 8; ++i) {
        v[i].x *= inv; v[i].y *= inv; v[i].z *= inv; v[i].w *= inv;
        *(float4*)(p + i * 256) = v[i];
    }
}

// ---------------------------------------------------------------------------
__global__ __launch_bounds__(256) void gate_mul(
    const float4* __restrict__ P1, const float4* __restrict__ P2,
    float4* __restrict__ out, int n4)
{
    int i = blockIdx.x * 256 + threadIdx.x;
    if (i < n4) {
        float4 a = P1[i], g = P2[i], o;
        o.x = a.x / (1.f + __expf(-g.x));
        o.y = a.y / (1.f + __expf(-g.y));
        o.z = a.z / (1.f + __expf(-g.z));
        o.w = a.w / (1.f + __expf(-g.w));
        out[i] = o;
    }
}

// ---------------------------------------------------------------------------
extern "C" void kernel_launch(void* const* d_in, const int* in_sizes, int n_in,
                              void* d_out, int out_size, void* d_ws, size_t ws_size,
                              hipStream_t stream)
{
    const float* x    = (const float*)d_in[0];
    const int*   mask = (const int*)d_in[1];
    const float* wq = (const float*)d_in[2];  const float* bq = (const float*)d_in[3];
    const float* wk = (const float*)d_in[4];  const float* bk = (const float*)d_in[5];
    const float* wv = (const float*)d_in[6];  const float* bv = (const float*)d_in[7];
    const float* wo = (const float*)d_in[8];  const float* bo = (const float*)d_in[9];
    const float* wg = (const float*)d_in[10]; const float* bg = (const float*)d_in[11];

    const int M = BB * SS;                  // 4096
    const size_t NTOK = (size_t)M * HH;     // 4,194,304

    float* out_main = (float*)d_out;
    float* attn     = (float*)d_out + NTOK; // [B,nh,S,S] raw scores -> weights

    float* Q   = (float*)d_ws;
    float* Kp  = Q  + NTOK;
    float* Vp  = Kp + NTOK;
    float* CTX = Vp + NTOK;
    float* VT  = Q;    // alias: Q dead after scores GEMM
    float* P1  = Kp;   // alias: K dead after scores
    float* P2  = Vp;   // alias: V dead after transpose

    dim3 pg(HH / 64, M / 128, 1);           // projections: (16, 32)
    mfma_gemm<64, 0><<<pg, 256, 0, stream>>>(x, wq, bq, Q,  HH, HH, HH, HH,
                                             0, 0, 0, 0, 0, 0, nullptr);
    mfma_gemm<64, 0><<<pg, 256, 0, stream>>>(x, wk, bk, Kp, HH, HH, HH, HH,
                                             0, 0, 0, 0, 0, 0, nullptr);
    mfma_gemm<64, 0><<<pg, 256, 0, stream>>>(x, wv, bv, Vp, HH, HH, HH, HH,
                                             0, 0, 0, 0, 0, 0, nullptr);

    // scores: per (b,h) Q[2048,64] @ K[2048,64]^T -> attn (raw, masked+scaled)
    dim3 sg(SS / 128, SS / 128, BB * NH);   // (16, 16, 32)
    mfma_gemm<128, 1><<<sg, 256, 0, stream>>>(Q, Kp, nullptr, attn,
        HD, HH, HH, SS,
        (long long)SS * HH, HD, (long long)SS * HH, HD,
        (long long)NH * SS * SS, (long long)SS * SS, mask);

    vtranspose<<<dim3(SS / 64, NH, BB), 256, 0, stream>>>(Vp, VT);
    softmax_rows<<<(BB * NH * SS) / 4, 256, 0, stream>>>(attn);

    // PV: per (b,h) P[2048,2048] @ VT[64,2048]^T -> ctx[b,q,h*64+d]
    mfma_gemm<64, 2><<<dim3(1, SS / 128, BB * NH), 256, 0, stream>>>(attn, VT, nullptr, CTX,
        SS, SS, SS, HH,
        (long long)NH * SS * SS, (long long)SS * SS,
        (long long)NH * HD * SS, (long long)HD * SS,
        (long long)SS * HH, HD, nullptr);

    mfma_gemm<64, 0><<<pg, 256, 0, stream>>>(CTX, wo, bo, P1, HH, HH, HH, HH,
                                             0, 0, 0, 0, 0, 0, nullptr);
    mfma_gemm<64, 0><<<pg, 256, 0, stream>>>(CTX, wg, bg, P2, HH, HH, HH, HH,
                                             0, 0, 0, 0, 0, 0, nullptr);

    int n4 = (int)(NTOK / 4);
    gate_mul<<<(n4 + 255) / 256, 256, 0, stream>>>(
        (const float4*)P1, (const float4*)P2, (float4*)out_main, n4);
}